// Round 2
// baseline (750.855 us; speedup 1.0000x reference)
//
#include <hip/hip_runtime.h>
#include <math.h>

#define N 4096
#define D 512
#define L 128

// ---------------- fast path (needs ~144 MB ws) ----------------
#define DTI 128
#define DTJ 256
#define DKD 16            // dbuf chunk
#define NCH (D / DKD)     // 32 chunks
#define DAS 132           // A LDS stride (2-way write banks, free)
#define DBS 284           // B LDS stride; mult of 4 (aligned b128), 284%32=28
                          // -> staging write banks 16*c4 spread = 2-way (free)
#define BUF_FLOATS (DKD * DAS + DKD * DBS)   // 6656 floats = 26624 B; x2 = 53248 B

// ---------------- fallback path (R3, ~25 MB ws) ----------------
#define PARTS 16
#define PARTJ (N / PARTS)
#define TI 128
#define TJ 64
#define KD 32
#define AS_STRIDE (TI + 4)
#define BS_STRIDE (TJ + 4)
#define DS_STRIDE (TJ + 4)
#define SMEM_FLOATS (TI * DS_STRIDE)

// acc += |t| in exactly one VOP3 instr (abs input modifier).
#define ACC_ABS(accv, t) \
  asm("v_add_f32 %0, %0, abs(%1)" : "+v"(accv) : "v"(t))

// Insert v into ascending sorted tk[0..15], dropping the old max.
__device__ __forceinline__ void topk_insert(float (&tk)[16], float v) {
  float x = v;
#pragma unroll
  for (int k = 0; k < 16; ++k) {
    float lo = fminf(x, tk[k]);
    float hi = fmaxf(x, tk[k]);
    tk[k] = lo;
    x = hi;
  }
}

// rec = latent @ W + b ; grid (N/8, 2), block 256.
__global__ __launch_bounds__(256) void linear_kernel(
    const float* __restrict__ lat_test, const float* __restrict__ lat_train,
    const float* __restrict__ W, const float* __restrict__ bias,
    float* __restrict__ rec_test, float* __restrict__ rec_train) {
  const float* __restrict__ lat = blockIdx.y ? lat_train : lat_test;
  float* __restrict__ out = blockIdx.y ? rec_train : rec_test;
  const int r0 = blockIdx.x * 8;
  const int t = threadIdx.x;

  __shared__ float ls[8 * L];
  {
    float4 v = *(const float4*)(lat + (size_t)r0 * L + t * 4);
    *(float4*)&ls[t * 4] = v;
  }
  __syncthreads();

  float acc[8][2];
#pragma unroll
  for (int r = 0; r < 8; ++r) { acc[r][0] = 0.f; acc[r][1] = 0.f; }

#pragma unroll 4
  for (int l = 0; l < L; ++l) {
    float w0 = W[l * D + t];
    float w1 = W[l * D + t + 256];
#pragma unroll
    for (int r = 0; r < 8; ++r) {
      float x = ls[r * L + l];
      acc[r][0] = fmaf(x, w0, acc[r][0]);
      acc[r][1] = fmaf(x, w1, acc[r][1]);
    }
  }
  float b0 = bias[t], b1 = bias[t + 256];
#pragma unroll
  for (int r = 0; r < 8; ++r) {
    out[(size_t)(r0 + r) * D + t] = acc[r][0] + b0;
    out[(size_t)(r0 + r) * D + t + 256] = acc[r][1] + b1;
  }
}

// One d-step of the 8x16 L1 tile: acc[r][c] += |av[r] - bv[c]|.
__device__ __forceinline__ void l1_step(float4 a0, float4 a1, float4 b0,
                                        float4 b1, float4 b2, float4 b3,
                                        float (&acc)[8][16]) {
  float av[8] = {a0.x, a0.y, a0.z, a0.w, a1.x, a1.y, a1.z, a1.w};
  float bv[16] = {b0.x, b0.y, b0.z, b0.w, b1.x, b1.y, b1.z, b1.w,
                  b2.x, b2.y, b2.z, b2.w, b3.x, b3.y, b3.z, b3.w};
#pragma unroll
  for (int r = 0; r < 8; ++r)
#pragma unroll
    for (int c = 0; c < 16; ++c) {
      float t = av[r] - bv[c];
      ACC_ABS(acc[r][c], t);
    }
}

// ============ FAST PATH ============
// L1 cdist, 128x256 tile, 8x16/thread, LDS double-buffer + explicit 2-deep
// REGISTER ping-pong on d: fragments for d+1 are loaded (program-order
// guaranteed) before the 512-instr compute of d, so lgkm latency is covered
// by a full d-step of VALU instead of relying on scheduler hoisting.
__global__ __launch_bounds__(256) __attribute__((amdgpu_waves_per_eu(2, 2)))
void dist_kernel(const float* __restrict__ Arec, const float* __restrict__ Bgt,
                 const float* __restrict__ Btr, float* __restrict__ dist) {
  const int i0 = blockIdx.x * DTI;
  const int j0 = blockIdx.y * DTJ;
  const int mat = blockIdx.z;
  const float* __restrict__ B = mat ? Btr : Bgt;
  float* __restrict__ out = dist + (size_t)mat * N * N;

  __shared__ float smem[2][BUF_FLOATS];  // 53248 B

  const int tid = threadIdx.x;
  const int tx = tid & 15;
  const int ty = tid >> 4;               // 0..15 -> 8 rows each
  const int aoff = 8 * ty;
  const int boff = 4 * tx + 4 * (tx >> 3);  // swizzled base; +72 per s

  // staging map: A chunk = 128 rows x 16 d = 512 float4 (2/thread);
  //              B chunk = 256 rows x 16 d = 1024 float4 (4/thread)
  const int r0 = tid >> 2;        // 0..63
  const int c4 = tid & 3;         // float4 index within 16-d chunk
  const int jw0 = r0 + 4 * (r0 >> 5);  // swizzled B column; +72 per 64 rows
  const float* apA0 = Arec + (size_t)(i0 + r0) * D + c4 * 4;
  const float* apA1 = Arec + (size_t)(i0 + r0 + 64) * D + c4 * 4;
  const float* bp0 = B + (size_t)(j0 + r0) * D + c4 * 4;
  const float* bp1 = B + (size_t)(j0 + r0 + 64) * D + c4 * 4;
  const float* bp2 = B + (size_t)(j0 + r0 + 128) * D + c4 * 4;
  const float* bp3 = B + (size_t)(j0 + r0 + 192) * D + c4 * 4;

  float acc[8][16];
#pragma unroll
  for (int r = 0; r < 8; ++r)
#pragma unroll
    for (int c = 0; c < 16; ++c) acc[r][c] = 0.f;

  float4 va0, va1, vb0, vb1, vb2, vb3;

#define STAGE_LOAD(off)                      \
  {                                          \
    va0 = *(const float4*)(apA0 + (off));    \
    va1 = *(const float4*)(apA1 + (off));    \
    vb0 = *(const float4*)(bp0 + (off));     \
    vb1 = *(const float4*)(bp1 + (off));     \
    vb2 = *(const float4*)(bp2 + (off));     \
    vb3 = *(const float4*)(bp3 + (off));     \
  }

#define STAGE_STORE(buf)                          \
  {                                               \
    float* As_ = (buf);                           \
    float* Bs_ = As_ + DKD * DAS;                 \
    As_[(4 * c4 + 0) * DAS + r0] = va0.x;         \
    As_[(4 * c4 + 1) * DAS + r0] = va0.y;         \
    As_[(4 * c4 + 2) * DAS + r0] = va0.z;         \
    As_[(4 * c4 + 3) * DAS + r0] = va0.w;         \
    As_[(4 * c4 + 0) * DAS + r0 + 64] = va1.x;    \
    As_[(4 * c4 + 1) * DAS + r0 + 64] = va1.y;    \
    As_[(4 * c4 + 2) * DAS + r0 + 64] = va1.z;    \
    As_[(4 * c4 + 3) * DAS + r0 + 64] = va1.w;    \
    Bs_[(4 * c4 + 0) * DBS + jw0] = vb0.x;        \
    Bs_[(4 * c4 + 1) * DBS + jw0] = vb0.y;        \
    Bs_[(4 * c4 + 2) * DBS + jw0] = vb0.z;        \
    Bs_[(4 * c4 + 3) * DBS + jw0] = vb0.w;        \
    Bs_[(4 * c4 + 0) * DBS + jw0 + 72] = vb1.x;   \
    Bs_[(4 * c4 + 1) * DBS + jw0 + 72] = vb1.y;   \
    Bs_[(4 * c4 + 2) * DBS + jw0 + 72] = vb1.z;   \
    Bs_[(4 * c4 + 3) * DBS + jw0 + 72] = vb1.w;   \
    Bs_[(4 * c4 + 0) * DBS + jw0 + 144] = vb2.x;  \
    Bs_[(4 * c4 + 1) * DBS + jw0 + 144] = vb2.y;  \
    Bs_[(4 * c4 + 2) * DBS + jw0 + 144] = vb2.z;  \
    Bs_[(4 * c4 + 3) * DBS + jw0 + 144] = vb2.w;  \
    Bs_[(4 * c4 + 0) * DBS + jw0 + 216] = vb3.x;  \
    Bs_[(4 * c4 + 1) * DBS + jw0 + 216] = vb3.y;  \
    Bs_[(4 * c4 + 2) * DBS + jw0 + 216] = vb3.z;  \
    Bs_[(4 * c4 + 3) * DBS + jw0 + 216] = vb3.w;  \
  }

#define LOADFRAG(A0v, A1v, B0v, B1v, B2v, B3v, dd)          \
  {                                                         \
    A0v = *(const float4*)&As[(dd) * DAS + aoff];           \
    A1v = *(const float4*)&As[(dd) * DAS + aoff + 4];       \
    B0v = *(const float4*)&Bs[(dd) * DBS + boff];           \
    B1v = *(const float4*)&Bs[(dd) * DBS + boff + 72];      \
    B2v = *(const float4*)&Bs[(dd) * DBS + boff + 144];     \
    B3v = *(const float4*)&Bs[(dd) * DBS + boff + 216];     \
  }

  // prologue: load chunk 0 and store into buffer 0
  STAGE_LOAD(0);
  STAGE_STORE(smem[0]);

#pragma unroll 1
  for (int chunk = 0; chunk < NCH; ++chunk) {
    __syncthreads();  // buf[chunk&1] fully staged for everyone
    // prefetch chunk+1 into regs (latency covered by 16-d compute below)
    if (chunk + 1 < NCH) {
      const int off = (chunk + 1) * DKD;
      STAGE_LOAD(off);
    }

    const float* As = smem[chunk & 1];
    const float* Bs = As + DKD * DAS;

    float4 pa0, pa1, pb0, pb1, pb2, pb3;
    float4 qa0, qa1, qb0, qb1, qb2, qb3;
    LOADFRAG(pa0, pa1, pb0, pb1, pb2, pb3, 0);

#pragma unroll 1
    for (int d = 0; d < DKD; d += 2) {
      // loads for d+1 issued BEFORE the 512-instr compute of d
      LOADFRAG(qa0, qa1, qb0, qb1, qb2, qb3, d + 1);
      l1_step(pa0, pa1, pb0, pb1, pb2, pb3, acc);
      // loads for d+2 (wraps to 0 on last iter; in-bounds, values unused)
      const int dn = (d + 2) & (DKD - 1);
      LOADFRAG(pa0, pa1, pb0, pb1, pb2, pb3, dn);
      l1_step(qa0, qa1, qb0, qb1, qb2, qb3, acc);
    }

    // store prefetched regs into the other buffer (its last readers were in
    // the previous iteration's compute, separated by this iter's barrier)
    if (chunk + 1 < NCH) {
      STAGE_STORE(smem[(chunk + 1) & 1]);
    }
  }

#pragma unroll
  for (int r = 0; r < 8; ++r) {
    float* dst = out + (size_t)(i0 + 8 * ty + r) * N + j0 + 4 * tx;
    *(float4*)(dst) = make_float4(acc[r][0], acc[r][1], acc[r][2], acc[r][3]);
    *(float4*)(dst + 64) = make_float4(acc[r][4], acc[r][5], acc[r][6], acc[r][7]);
    *(float4*)(dst + 128) = make_float4(acc[r][8], acc[r][9], acc[r][10], acc[r][11]);
    *(float4*)(dst + 192) = make_float4(acc[r][12], acc[r][13], acc[r][14], acc[r][15]);
  }
#undef STAGE_LOAD
#undef STAGE_STORE
#undef LOADFRAG
}

// One WAVE per row (4 rows per 256-block, grid 2N/4): insert-filtered scan of
// 64 elems/lane, then 6 shfl_xor bitonic merge levels. No LDS, no barriers.
__global__ __launch_bounds__(256) void row_topk_kernel(
    const float* __restrict__ dist, float* __restrict__ scores) {
  const int wave = threadIdx.x >> 6;
  const int lane = threadIdx.x & 63;
  const int row = blockIdx.x * 4 + wave;
  const float* __restrict__ p = dist + (size_t)row * N;

  float tk[16];
#pragma unroll
  for (int k = 0; k < 16; ++k) tk[k] = 3.0e38f;

#pragma unroll 1
  for (int q = 0; q < 16; ++q) {  // each q: wave reads 1 KB contiguous
    float4 v = *(const float4*)(p + q * 256 + lane * 4);
    if (v.x < tk[15]) topk_insert(tk, v.x);
    if (v.y < tk[15]) topk_insert(tk, v.y);
    if (v.z < tk[15]) topk_insert(tk, v.z);
    if (v.w < tk[15]) topk_insert(tk, v.w);
  }

  // recursive-doubling merge: after level m, lanes in each 2m-group identical
#pragma unroll
  for (int m = 1; m < 64; m <<= 1) {
    float oth[16];
#pragma unroll
    for (int k = 0; k < 16; ++k) oth[k] = __shfl_xor(tk[k], m, 64);
    // half-cleaner: lowest 16 of union, result is bitonic
    float lo[16];
#pragma unroll
    for (int k = 0; k < 16; ++k) lo[k] = fminf(tk[k], oth[15 - k]);
    // bitonic sort of a bitonic 16-seq: stages 8,4,2,1 (constant-indexed)
#pragma unroll
    for (int dlt = 8; dlt >= 1; dlt >>= 1) {
#pragma unroll
      for (int i = 0; i < 16; ++i) {
        if ((i & dlt) == 0 && (i + dlt) < 16) {
          float a = lo[i], b = lo[i + dlt];
          lo[i] = fminf(a, b);
          lo[i + dlt] = fmaxf(a, b);
        }
      }
    }
#pragma unroll
    for (int k = 0; k < 16; ++k) tk[k] = lo[k];
  }

  if (lane == 0) {
    float s = 0.f;
#pragma unroll
    for (int k = 0; k < 16; ++k) s += 1.0f / tk[k];
    scores[row] = s * (1.0f / 16.0f);
  }
}

// ============ FALLBACK PATH (R3, proven) ============
__global__ __launch_bounds__(256) void dist_topk_kernel(
    const float* __restrict__ Arec, const float* __restrict__ Bgt,
    const float* __restrict__ Btr, float* __restrict__ cand) {
  const int itile = blockIdx.x;
  const int part = blockIdx.y;
  const int mat = blockIdx.z;
  const float* __restrict__ B = mat ? Btr : Bgt;
  const int i0 = itile * TI;
  const int jbase = part * PARTJ;

  __shared__ float smem[SMEM_FLOATS];
  float* As = smem;
  float* Bs = smem + KD * AS_STRIDE;
  float* distS = smem;

  const int tid = threadIdx.x;
  const int tx = tid & 15;
  const int ty = tid >> 4;
  const int srow = tid >> 1;
  const int shalf = tid & 1;
  const int scol = shalf * 32;

  float tk[16];
#pragma unroll
  for (int k = 0; k < 16; ++k) tk[k] = 3.0e38f;

  for (int jc = 0; jc < PARTJ; jc += TJ) {
    float acc[8][4];
#pragma unroll
    for (int r = 0; r < 8; ++r)
#pragma unroll
      for (int c = 0; c < 4; ++c) acc[r][c] = 0.f;

    for (int d0 = 0; d0 < D; d0 += KD) {
      __syncthreads();
#pragma unroll
      for (int s = 0; s < 4; ++s) {
        int f4 = tid + s * 256;
        int r = f4 >> 3;
        int c4 = f4 & 7;
        float4 v = *(const float4*)(Arec + (size_t)(i0 + r) * D + d0 + c4 * 4);
        As[(4 * c4 + 0) * AS_STRIDE + r] = v.x;
        As[(4 * c4 + 1) * AS_STRIDE + r] = v.y;
        As[(4 * c4 + 2) * AS_STRIDE + r] = v.z;
        As[(4 * c4 + 3) * AS_STRIDE + r] = v.w;
      }
#pragma unroll
      for (int s = 0; s < 2; ++s) {
        int f4 = tid + s * 256;
        int r = f4 >> 3;
        int c4 = f4 & 7;
        float4 v = *(const float4*)(B + (size_t)(jbase + jc + r) * D + d0 + c4 * 4);
        Bs[(4 * c4 + 0) * BS_STRIDE + r] = v.x;
        Bs[(4 * c4 + 1) * BS_STRIDE + r] = v.y;
        Bs[(4 * c4 + 2) * BS_STRIDE + r] = v.z;
        Bs[(4 * c4 + 3) * BS_STRIDE + r] = v.w;
      }
      __syncthreads();

#pragma unroll
      for (int d = 0; d < KD; ++d) {
        float4 a0 = *(const float4*)&As[d * AS_STRIDE + 8 * ty];
        float4 a1 = *(const float4*)&As[d * AS_STRIDE + 8 * ty + 4];
        float4 bv4 = *(const float4*)&Bs[d * BS_STRIDE + 4 * tx];
        float av[8] = {a0.x, a0.y, a0.z, a0.w, a1.x, a1.y, a1.z, a1.w};
        float bv[4] = {bv4.x, bv4.y, bv4.z, bv4.w};
#pragma unroll
        for (int r = 0; r < 8; ++r)
#pragma unroll
          for (int c = 0; c < 4; ++c) acc[r][c] += __builtin_fabsf(av[r] - bv[c]);
      }
    }

    __syncthreads();
#pragma unroll
    for (int r = 0; r < 8; ++r)
      *(float4*)&distS[(8 * ty + r) * DS_STRIDE + 4 * tx] =
          make_float4(acc[r][0], acc[r][1], acc[r][2], acc[r][3]);
    __syncthreads();

#pragma unroll 1
    for (int j4 = 0; j4 < 8; ++j4) {
      float4 v = *(const float4*)&distS[srow * DS_STRIDE + scol + j4 * 4];
      if (v.x < tk[15]) topk_insert(tk, v.x);
      if (v.y < tk[15]) topk_insert(tk, v.y);
      if (v.z < tk[15]) topk_insert(tk, v.z);
      if (v.w < tk[15]) topk_insert(tk, v.w);
    }
  }

  __syncthreads();
  float* mergeS = smem;
#pragma unroll
  for (int k4 = 0; k4 < 4; ++k4)
    *(float4*)&mergeS[srow * 32 + shalf * 16 + k4 * 4] =
        make_float4(tk[k4 * 4], tk[k4 * 4 + 1], tk[k4 * 4 + 2], tk[k4 * 4 + 3]);
  __syncthreads();

  if (tid < TI) {
    const float* LA = &mergeS[tid * 32];
    const float* LB = LA + 16;
    const int row = i0 + tid;
    float* dst = cand + ((size_t)((mat * PARTS + part) * N) + row) * 16;
    int ia = 0, ib = 0;
#pragma unroll 1
    for (int k = 0; k < 16; ++k) {
      float a = LA[ia < 16 ? ia : 15];
      float b = LB[ib < 16 ? ib : 15];
      bool takeA = (ib >= 16) || (ia < 16 && a <= b);
      dst[k] = takeA ? a : b;
      ia += takeA ? 1 : 0;
      ib += takeA ? 0 : 1;
    }
  }
}

__global__ __launch_bounds__(256) void merge_kernel(
    const float* __restrict__ cand, float* __restrict__ scores) {
  const int gid = blockIdx.x * 256 + threadIdx.x;
  if (gid >= 2 * N) return;
  const int m = gid >> 12;
  const int row = gid & (N - 1);

  float tk[16];
#pragma unroll
  for (int k = 0; k < 16; ++k) tk[k] = 3.0e38f;

  for (int p = 0; p < PARTS; ++p) {
    const float* lp = cand + ((size_t)((m * PARTS + p) * N) + row) * 16;
#pragma unroll 1
    for (int k = 0; k < 16; ++k) {
      float v = lp[k];
      if (v >= tk[15]) break;
      topk_insert(tk, v);
    }
  }
  float s = 0.f;
#pragma unroll
  for (int k = 0; k < 16; ++k) s += 1.0f / tk[k];
  scores[(size_t)m * N + row] = s * (1.0f / 16.0f);
}

// losses = relu(neg - pos); huber(delta=1) vs 0; mean. Single block.
__global__ __launch_bounds__(256) void loss_kernel(
    const float* __restrict__ scores, float* __restrict__ out) {
  const int tid = threadIdx.x;
  float s = 0.f;
  for (int i = tid; i < N; i += 256) {
    float l = scores[N + i] - scores[i];
    l = fmaxf(l, 0.f);
    s += (l <= 1.f) ? 0.5f * l * l : (l - 0.5f);
  }
#pragma unroll
  for (int off = 32; off > 0; off >>= 1) s += __shfl_down(s, off, 64);
  __shared__ float ws[4];
  if ((tid & 63) == 0) ws[tid >> 6] = s;
  __syncthreads();
  if (tid == 0) {
    float t = ws[0] + ws[1] + ws[2] + ws[3];
    out[0] = t * (1.0f / (float)N);
  }
}

extern "C" void kernel_launch(void* const* d_in, const int* in_sizes, int n_in,
                              void* d_out, int out_size, void* d_ws, size_t ws_size,
                              hipStream_t stream) {
  const float* gt_vals = (const float*)d_in[0];
  const float* train_latent = (const float*)d_in[1];
  const float* test_latent = (const float*)d_in[2];
  const float* W = (const float*)d_in[3];
  const float* b = (const float*)d_in[4];
  float* out = (float*)d_out;

  char* ws = (char*)d_ws;
  const size_t REC = 8388608;          // 8 MB each
  const size_t DIST = 134217728;       // 128 MB
  const size_t NEED_FAST = 2 * REC + DIST + 32768;

  float* rec_test = (float*)(ws);
  float* rec_train = (float*)(ws + REC);

  linear_kernel<<<dim3(N / 8, 2), 256, 0, stream>>>(
      test_latent, train_latent, W, b, rec_test, rec_train);

  if (ws_size >= NEED_FAST) {
    float* dist = (float*)(ws + 2 * REC);
    float* scores = (float*)(ws + 2 * REC + DIST);
    dist_kernel<<<dim3(N / DTI, N / DTJ, 2), 256, 0, stream>>>(
        rec_test, gt_vals, rec_train, dist);
    row_topk_kernel<<<(2 * N) / 4, 256, 0, stream>>>(dist, scores);
    loss_kernel<<<1, 256, 0, stream>>>(scores, out);
  } else {
    float* cand = (float*)(ws + 2 * REC);                 // 8 MB
    float* scores = (float*)(ws + 2 * REC + 8388608);     // 32 KB
    dist_topk_kernel<<<dim3(N / TI, PARTS, 2), 256, 0, stream>>>(
        rec_test, gt_vals, rec_train, cand);
    merge_kernel<<<(2 * N) / 256, 256, 0, stream>>>(cand, scores);
    loss_kernel<<<1, 256, 0, stream>>>(scores, out);
  }
}

// Round 3
// 418.299 us; speedup vs baseline: 1.7950x; 1.7950x over previous
//
#include <hip/hip_runtime.h>
#include <math.h>

#define N 4096
#define D 512
#define L 128

// ---------------- fast path (needs 144 MB ws) ----------------
// dist via v_sad_u16 on 16-bit fixed-point (scale 2^12, bias 32768), packed
// 2 dims per u32, transposed layouts [pd][N]. Zero LDS in the hot kernel.
#define BI 64            // rows per block (16 per wave)
#define BJ 128           // cols per block (2 per lane)
#define NPD (D / 2)      // 256 packed dims

// ---------------- fallback path (R3, ~25 MB ws) ----------------
#define PARTS 16
#define PARTJ (N / PARTS)
#define TI 128
#define TJ 64
#define KD 32
#define AS_STRIDE (TI + 4)
#define BS_STRIDE (TJ + 4)
#define DS_STRIDE (TJ + 4)
#define SMEM_FLOATS (TI * DS_STRIDE)

__device__ __forceinline__ unsigned sad16(unsigned a, unsigned b, unsigned c) {
#if __has_builtin(__builtin_amdgcn_sad_u16)
  return __builtin_amdgcn_sad_u16(a, b, c);
#else
  unsigned d;
  asm("v_sad_u16 %0, %1, %2, %3" : "=v"(d) : "v"(a), "v"(b), "v"(c));
  return d;
#endif
}

// quantize+pack two consecutive dims into one u32 (u16 lanes, bias 32768)
__device__ __forceinline__ unsigned pack2(float x, float y) {
  int qx = __float2int_rn(x * 4096.0f);
  int qy = __float2int_rn(y * 4096.0f);
  qx = min(max(qx, -32768), 32767);
  qy = min(max(qy, -32768), 32767);
  return (unsigned)(qx + 32768) | ((unsigned)(qy + 32768) << 16);
}

// Insert v into ascending sorted tk[0..15], dropping the old max.
__device__ __forceinline__ void topk_insert(float (&tk)[16], float v) {
  float x = v;
#pragma unroll
  for (int k = 0; k < 16; ++k) {
    float lo = fminf(x, tk[k]);
    float hi = fmaxf(x, tk[k]);
    tk[k] = lo;
    x = hi;
  }
}

// rec = latent @ W + b ; grid (N/8, 2), block 256.
__global__ __launch_bounds__(256) void linear_kernel(
    const float* __restrict__ lat_test, const float* __restrict__ lat_train,
    const float* __restrict__ W, const float* __restrict__ bias,
    float* __restrict__ rec_test, float* __restrict__ rec_train) {
  const float* __restrict__ lat = blockIdx.y ? lat_train : lat_test;
  float* __restrict__ out = blockIdx.y ? rec_train : rec_test;
  const int r0 = blockIdx.x * 8;
  const int t = threadIdx.x;

  __shared__ float ls[8 * L];
  {
    float4 v = *(const float4*)(lat + (size_t)r0 * L + t * 4);
    *(float4*)&ls[t * 4] = v;
  }
  __syncthreads();

  float acc[8][2];
#pragma unroll
  for (int r = 0; r < 8; ++r) { acc[r][0] = 0.f; acc[r][1] = 0.f; }

#pragma unroll 4
  for (int l = 0; l < L; ++l) {
    float w0 = W[l * D + t];
    float w1 = W[l * D + t + 256];
#pragma unroll
    for (int r = 0; r < 8; ++r) {
      float x = ls[r * L + l];
      acc[r][0] = fmaf(x, w0, acc[r][0]);
      acc[r][1] = fmaf(x, w1, acc[r][1]);
    }
  }
  float b0 = bias[t], b1 = bias[t + 256];
#pragma unroll
  for (int r = 0; r < 8; ++r) {
    out[(size_t)(r0 + r) * D + t] = acc[r][0] + b0;
    out[(size_t)(r0 + r) * D + t + 256] = acc[r][1] + b1;
  }
}

// ============ FAST PATH ============
// Quantize + pack + transpose one 64-row tile of one source matrix into
// dst[pd][N] layout. grid (N/64, 3): y=0 gt, y=1 rec_test, y=2 rec_train.
#define PKR 64
__global__ __launch_bounds__(256) void pack_kernel(
    const float* __restrict__ gt, const float* __restrict__ rec_test,
    const float* __restrict__ rec_train, unsigned* __restrict__ Gq,
    unsigned* __restrict__ Aq, unsigned* __restrict__ Tq) {
  const int which = blockIdx.y;
  const float* __restrict__ src =
      which == 0 ? gt : (which == 1 ? rec_test : rec_train);
  unsigned* __restrict__ dst = which == 0 ? Gq : (which == 1 ? Aq : Tq);
  const int i0 = blockIdx.x * PKR;
  const int tid = threadIdx.x;

  __shared__ unsigned ls[PKR][NPD + 1];  // +1 pad -> conflict-free col reads

  // 64 rows x 128 float4 = 8192 float4; 32 per thread, coalesced 1KB/wave
#pragma unroll 4
  for (int s = 0; s < 32; ++s) {
    int flat = tid + s * 256;
    int row = flat >> 7;
    int c4 = flat & 127;
    float4 v = *(const float4*)(src + (size_t)(i0 + row) * D + c4 * 4);
    ls[row][c4 * 2] = pack2(v.x, v.y);
    ls[row][c4 * 2 + 1] = pack2(v.z, v.w);
  }
  __syncthreads();

  // write out transposed: wave writes 64 consecutive i per pd (256B stores)
#pragma unroll 4
  for (int s = 0; s < 64; ++s) {
    int flat = tid + s * 256;
    int pd = flat >> 6;
    int i = flat & 63;
    dst[(size_t)pd * N + i0 + i] = ls[i][pd];
  }
}

// L1 cdist on packed u16 pairs. Block = 4 waves; wave owns 16 rows (A values
// wave-uniform -> scalar loads), lane owns 2 cols. 32 v_sad_u16 per pd per
// thread = 4 element-pairs per VALU instr. No LDS, no barriers.
__global__ __launch_bounds__(256) __attribute__((amdgpu_waves_per_eu(6)))
void dist_sad_kernel(const unsigned* __restrict__ Aq,
                     const unsigned* __restrict__ Gq,
                     const unsigned* __restrict__ Tq,
                     float* __restrict__ dist) {
  const int i0 = blockIdx.x * BI;
  const int j0 = blockIdx.y * BJ;
  const int mat = blockIdx.z;
  const unsigned* __restrict__ Bq = mat ? Tq : Gq;
  float* __restrict__ out = dist + (size_t)mat * N * N;

  const int wave = threadIdx.x >> 6;
  const int lane = threadIdx.x & 63;
  const int iw = __builtin_amdgcn_readfirstlane(i0 + wave * 16);

  const unsigned* __restrict__ ap = Aq + iw;            // uniform per wave
  const unsigned* __restrict__ bp = Bq + j0 + 2 * lane; // coalesced per wave

  unsigned acc[16][2];
#pragma unroll
  for (int r = 0; r < 16; ++r) { acc[r][0] = 0u; acc[r][1] = 0u; }

#pragma unroll 4
  for (int pd = 0; pd < NPD; ++pd) {
    uint4 a0 = *(const uint4*)(ap);
    uint4 a1 = *(const uint4*)(ap + 4);
    uint4 a2 = *(const uint4*)(ap + 8);
    uint4 a3 = *(const uint4*)(ap + 12);
    uint2 b = *(const uint2*)(bp);
    ap += N;
    bp += N;
#define SADQ(q, base)                                      \
    acc[base + 0][0] = sad16(q.x, b.x, acc[base + 0][0]);  \
    acc[base + 0][1] = sad16(q.x, b.y, acc[base + 0][1]);  \
    acc[base + 1][0] = sad16(q.y, b.x, acc[base + 1][0]);  \
    acc[base + 1][1] = sad16(q.y, b.y, acc[base + 1][1]);  \
    acc[base + 2][0] = sad16(q.z, b.x, acc[base + 2][0]);  \
    acc[base + 2][1] = sad16(q.z, b.y, acc[base + 2][1]);  \
    acc[base + 3][0] = sad16(q.w, b.x, acc[base + 3][0]);  \
    acc[base + 3][1] = sad16(q.w, b.y, acc[base + 3][1]);
    SADQ(a0, 0) SADQ(a1, 4) SADQ(a2, 8) SADQ(a3, 12)
#undef SADQ
  }

  const float sc = 1.0f / 4096.0f;
#pragma unroll
  for (int r = 0; r < 16; ++r) {
    float2 dv = make_float2((float)acc[r][0] * sc, (float)acc[r][1] * sc);
    *(float2*)(out + (size_t)(iw + r) * N + j0 + 2 * lane) = dv;
  }
}

// One WAVE per row (4 rows per 256-block, grid 2N/4): insert-filtered scan of
// 64 elems/lane, then 6 shfl_xor bitonic merge levels. No LDS, no barriers.
__global__ __launch_bounds__(256) void row_topk_kernel(
    const float* __restrict__ dist, float* __restrict__ scores) {
  const int wave = threadIdx.x >> 6;
  const int lane = threadIdx.x & 63;
  const int row = blockIdx.x * 4 + wave;
  const float* __restrict__ p = dist + (size_t)row * N;

  float tk[16];
#pragma unroll
  for (int k = 0; k < 16; ++k) tk[k] = 3.0e38f;

#pragma unroll 1
  for (int q = 0; q < 16; ++q) {  // each q: wave reads 1 KB contiguous
    float4 v = *(const float4*)(p + q * 256 + lane * 4);
    if (v.x < tk[15]) topk_insert(tk, v.x);
    if (v.y < tk[15]) topk_insert(tk, v.y);
    if (v.z < tk[15]) topk_insert(tk, v.z);
    if (v.w < tk[15]) topk_insert(tk, v.w);
  }

  // recursive-doubling merge: after level m, lanes in each 2m-group identical
#pragma unroll
  for (int m = 1; m < 64; m <<= 1) {
    float oth[16];
#pragma unroll
    for (int k = 0; k < 16; ++k) oth[k] = __shfl_xor(tk[k], m, 64);
    // half-cleaner: lowest 16 of union, result is bitonic
    float lo[16];
#pragma unroll
    for (int k = 0; k < 16; ++k) lo[k] = fminf(tk[k], oth[15 - k]);
    // bitonic sort of a bitonic 16-seq: stages 8,4,2,1 (constant-indexed)
#pragma unroll
    for (int dlt = 8; dlt >= 1; dlt >>= 1) {
#pragma unroll
      for (int i = 0; i < 16; ++i) {
        if ((i & dlt) == 0 && (i + dlt) < 16) {
          float a = lo[i], b = lo[i + dlt];
          lo[i] = fminf(a, b);
          lo[i + dlt] = fmaxf(a, b);
        }
      }
    }
#pragma unroll
    for (int k = 0; k < 16; ++k) tk[k] = lo[k];
  }

  if (lane == 0) {
    float s = 0.f;
#pragma unroll
    for (int k = 0; k < 16; ++k) s += 1.0f / tk[k];
    scores[row] = s * (1.0f / 16.0f);
  }
}

// ============ FALLBACK PATH (R3, proven) ============
__global__ __launch_bounds__(256) void dist_topk_kernel(
    const float* __restrict__ Arec, const float* __restrict__ Bgt,
    const float* __restrict__ Btr, float* __restrict__ cand) {
  const int itile = blockIdx.x;
  const int part = blockIdx.y;
  const int mat = blockIdx.z;
  const float* __restrict__ B = mat ? Btr : Bgt;
  const int i0 = itile * TI;
  const int jbase = part * PARTJ;

  __shared__ float smem[SMEM_FLOATS];
  float* As = smem;
  float* Bs = smem + KD * AS_STRIDE;
  float* distS = smem;

  const int tid = threadIdx.x;
  const int tx = tid & 15;
  const int ty = tid >> 4;
  const int srow = tid >> 1;
  const int shalf = tid & 1;
  const int scol = shalf * 32;

  float tk[16];
#pragma unroll
  for (int k = 0; k < 16; ++k) tk[k] = 3.0e38f;

  for (int jc = 0; jc < PARTJ; jc += TJ) {
    float acc[8][4];
#pragma unroll
    for (int r = 0; r < 8; ++r)
#pragma unroll
      for (int c = 0; c < 4; ++c) acc[r][c] = 0.f;

    for (int d0 = 0; d0 < D; d0 += KD) {
      __syncthreads();
#pragma unroll
      for (int s = 0; s < 4; ++s) {
        int f4 = tid + s * 256;
        int r = f4 >> 3;
        int c4 = f4 & 7;
        float4 v = *(const float4*)(Arec + (size_t)(i0 + r) * D + d0 + c4 * 4);
        As[(4 * c4 + 0) * AS_STRIDE + r] = v.x;
        As[(4 * c4 + 1) * AS_STRIDE + r] = v.y;
        As[(4 * c4 + 2) * AS_STRIDE + r] = v.z;
        As[(4 * c4 + 3) * AS_STRIDE + r] = v.w;
      }
#pragma unroll
      for (int s = 0; s < 2; ++s) {
        int f4 = tid + s * 256;
        int r = f4 >> 3;
        int c4 = f4 & 7;
        float4 v = *(const float4*)(B + (size_t)(jbase + jc + r) * D + d0 + c4 * 4);
        Bs[(4 * c4 + 0) * BS_STRIDE + r] = v.x;
        Bs[(4 * c4 + 1) * BS_STRIDE + r] = v.y;
        Bs[(4 * c4 + 2) * BS_STRIDE + r] = v.z;
        Bs[(4 * c4 + 3) * BS_STRIDE + r] = v.w;
      }
      __syncthreads();

#pragma unroll
      for (int d = 0; d < KD; ++d) {
        float4 a0 = *(const float4*)&As[d * AS_STRIDE + 8 * ty];
        float4 a1 = *(const float4*)&As[d * AS_STRIDE + 8 * ty + 4];
        float4 bv4 = *(const float4*)&Bs[d * BS_STRIDE + 4 * tx];
        float av[8] = {a0.x, a0.y, a0.z, a0.w, a1.x, a1.y, a1.z, a1.w};
        float bv[4] = {bv4.x, bv4.y, bv4.z, bv4.w};
#pragma unroll
        for (int r = 0; r < 8; ++r)
#pragma unroll
          for (int c = 0; c < 4; ++c) acc[r][c] += __builtin_fabsf(av[r] - bv[c]);
      }
    }

    __syncthreads();
#pragma unroll
    for (int r = 0; r < 8; ++r)
      *(float4*)&distS[(8 * ty + r) * DS_STRIDE + 4 * tx] =
          make_float4(acc[r][0], acc[r][1], acc[r][2], acc[r][3]);
    __syncthreads();

#pragma unroll 1
    for (int j4 = 0; j4 < 8; ++j4) {
      float4 v = *(const float4*)&distS[srow * DS_STRIDE + scol + j4 * 4];
      if (v.x < tk[15]) topk_insert(tk, v.x);
      if (v.y < tk[15]) topk_insert(tk, v.y);
      if (v.z < tk[15]) topk_insert(tk, v.z);
      if (v.w < tk[15]) topk_insert(tk, v.w);
    }
  }

  __syncthreads();
  float* mergeS = smem;
#pragma unroll
  for (int k4 = 0; k4 < 4; ++k4)
    *(float4*)&mergeS[srow * 32 + shalf * 16 + k4 * 4] =
        make_float4(tk[k4 * 4], tk[k4 * 4 + 1], tk[k4 * 4 + 2], tk[k4 * 4 + 3]);
  __syncthreads();

  if (tid < TI) {
    const float* LA = &mergeS[tid * 32];
    const float* LB = LA + 16;
    const int row = i0 + tid;
    float* dst = cand + ((size_t)((mat * PARTS + part) * N) + row) * 16;
    int ia = 0, ib = 0;
#pragma unroll 1
    for (int k = 0; k < 16; ++k) {
      float a = LA[ia < 16 ? ia : 15];
      float b = LB[ib < 16 ? ib : 15];
      bool takeA = (ib >= 16) || (ia < 16 && a <= b);
      dst[k] = takeA ? a : b;
      ia += takeA ? 1 : 0;
      ib += takeA ? 0 : 1;
    }
  }
}

__global__ __launch_bounds__(256) void merge_kernel(
    const float* __restrict__ cand, float* __restrict__ scores) {
  const int gid = blockIdx.x * 256 + threadIdx.x;
  if (gid >= 2 * N) return;
  const int m = gid >> 12;
  const int row = gid & (N - 1);

  float tk[16];
#pragma unroll
  for (int k = 0; k < 16; ++k) tk[k] = 3.0e38f;

  for (int p = 0; p < PARTS; ++p) {
    const float* lp = cand + ((size_t)((m * PARTS + p) * N) + row) * 16;
#pragma unroll 1
    for (int k = 0; k < 16; ++k) {
      float v = lp[k];
      if (v >= tk[15]) break;
      topk_insert(tk, v);
    }
  }
  float s = 0.f;
#pragma unroll
  for (int k = 0; k < 16; ++k) s += 1.0f / tk[k];
  scores[(size_t)m * N + row] = s * (1.0f / 16.0f);
}

// losses = relu(neg - pos); huber(delta=1) vs 0; mean. Single block.
__global__ __launch_bounds__(256) void loss_kernel(
    const float* __restrict__ scores, float* __restrict__ out) {
  const int tid = threadIdx.x;
  float s = 0.f;
  for (int i = tid; i < N; i += 256) {
    float l = scores[N + i] - scores[i];
    l = fmaxf(l, 0.f);
    s += (l <= 1.f) ? 0.5f * l * l : (l - 0.5f);
  }
#pragma unroll
  for (int off = 32; off > 0; off >>= 1) s += __shfl_down(s, off, 64);
  __shared__ float ws[4];
  if ((tid & 63) == 0) ws[tid >> 6] = s;
  __syncthreads();
  if (tid == 0) {
    float t = ws[0] + ws[1] + ws[2] + ws[3];
    out[0] = t * (1.0f / (float)N);
  }
}

extern "C" void kernel_launch(void* const* d_in, const int* in_sizes, int n_in,
                              void* d_out, int out_size, void* d_ws, size_t ws_size,
                              hipStream_t stream) {
  const float* gt_vals = (const float*)d_in[0];
  const float* train_latent = (const float*)d_in[1];
  const float* test_latent = (const float*)d_in[2];
  const float* W = (const float*)d_in[3];
  const float* b = (const float*)d_in[4];
  float* out = (float*)d_out;

  char* ws = (char*)d_ws;
  const size_t MB = 1048576;
  const size_t REC = 8 * MB;
  const size_t DIST = 128 * MB;
  const size_t NEED_FAST = 2 * REC + DIST + 32768;

  if (ws_size >= NEED_FAST) {
    // layout: [0,4M) Aq(test), [4,8M) Tq(train), [8,12M) Gq(gt),
    // [12M,+32K) scores, [16M,144M) dist; rec f32 live transiently at
    // [16M,24M)/[24M,32M) inside the dist region (dead before dist write).
    unsigned* Aq = (unsigned*)(ws);
    unsigned* Tq = (unsigned*)(ws + 4 * MB);
    unsigned* Gq = (unsigned*)(ws + 8 * MB);
    float* scores = (float*)(ws + 12 * MB);
    float* dist = (float*)(ws + 16 * MB);
    float* rec_test = (float*)(ws + 16 * MB);
    float* rec_train = (float*)(ws + 24 * MB);

    linear_kernel<<<dim3(N / 8, 2), 256, 0, stream>>>(
        test_latent, train_latent, W, b, rec_test, rec_train);
    pack_kernel<<<dim3(N / PKR, 3), 256, 0, stream>>>(
        gt_vals, rec_test, rec_train, Gq, Aq, Tq);
    dist_sad_kernel<<<dim3(N / BI, N / BJ, 2), 256, 0, stream>>>(
        Aq, Gq, Tq, dist);
    row_topk_kernel<<<(2 * N) / 4, 256, 0, stream>>>(dist, scores);
    loss_kernel<<<1, 256, 0, stream>>>(scores, out);
  } else {
    float* rec_test = (float*)(ws);
    float* rec_train = (float*)(ws + REC);
    float* cand = (float*)(ws + 2 * REC);                 // 8 MB
    float* scores = (float*)(ws + 2 * REC + 8388608);     // 32 KB
    linear_kernel<<<dim3(N / 8, 2), 256, 0, stream>>>(
        test_latent, train_latent, W, b, rec_test, rec_train);
    dist_topk_kernel<<<dim3(N / TI, PARTS, 2), 256, 0, stream>>>(
        rec_test, gt_vals, rec_train, cand);
    merge_kernel<<<(2 * N) / 256, 256, 0, stream>>>(cand, scores);
    loss_kernel<<<1, 256, 0, stream>>>(scores, out);
  }
}

// Round 4
// 290.237 us; speedup vs baseline: 2.5870x; 1.4412x over previous
//
#include <hip/hip_runtime.h>
#include <math.h>

#define N 4096
#define D 512
#define L 128

// ---------------- fast path (needs 144 MB ws) ----------------
// dist via v_sad_u8 on 8-bit fixed-point (scale 16, bias 128), packed
// 4 dims per u32, transposed layouts [pd][N]. Zero LDS in the hot kernel.
// v_sad_u16 measured ~4cyc/wave64 on gfx950 (R3: VALUBusy 86 == instrs*4/wall);
// v_sad_u8 assumed same rate -> 2x pairs/instr.
#define BI 64            // rows per block (16 per wave)
#define BJ 128           // cols per block (2 per lane)
#define NP8 (D / 4)      // 128 packed dims (4 bytes each)

// ---------------- fallback path (R3, ~25 MB ws) ----------------
#define PARTS 16
#define PARTJ (N / PARTS)
#define TI 128
#define TJ 64
#define KD 32
#define AS_STRIDE (TI + 4)
#define BS_STRIDE (TJ + 4)
#define DS_STRIDE (TJ + 4)
#define SMEM_FLOATS (TI * DS_STRIDE)

__device__ __forceinline__ unsigned sad8(unsigned a, unsigned b, unsigned c) {
#if __has_builtin(__builtin_amdgcn_sad_u8)
  return __builtin_amdgcn_sad_u8(a, b, c);
#else
  unsigned d;
  asm("v_sad_u8 %0, %1, %2, %3" : "=v"(d) : "v"(a), "v"(b), "v"(c));
  return d;
#endif
}

// quantize+pack four consecutive dims into one u32 (u8 lanes, bias 128)
__device__ __forceinline__ unsigned pack4(float4 v) {
  int q0 = min(max(__float2int_rn(v.x * 16.0f), -128), 127) + 128;
  int q1 = min(max(__float2int_rn(v.y * 16.0f), -128), 127) + 128;
  int q2 = min(max(__float2int_rn(v.z * 16.0f), -128), 127) + 128;
  int q3 = min(max(__float2int_rn(v.w * 16.0f), -128), 127) + 128;
  return (unsigned)q0 | ((unsigned)q1 << 8) | ((unsigned)q2 << 16) |
         ((unsigned)q3 << 24);
}

// Insert v into ascending sorted tk[0..15], dropping the old max.
__device__ __forceinline__ void topk_insert(float (&tk)[16], float v) {
  float x = v;
#pragma unroll
  for (int k = 0; k < 16; ++k) {
    float lo = fminf(x, tk[k]);
    float hi = fmaxf(x, tk[k]);
    tk[k] = lo;
    x = hi;
  }
}

// rec = latent @ W + b ; grid (N/8, 2), block 256.
__global__ __launch_bounds__(256) void linear_kernel(
    const float* __restrict__ lat_test, const float* __restrict__ lat_train,
    const float* __restrict__ W, const float* __restrict__ bias,
    float* __restrict__ rec_test, float* __restrict__ rec_train) {
  const float* __restrict__ lat = blockIdx.y ? lat_train : lat_test;
  float* __restrict__ out = blockIdx.y ? rec_train : rec_test;
  const int r0 = blockIdx.x * 8;
  const int t = threadIdx.x;

  __shared__ float ls[8 * L];
  {
    float4 v = *(const float4*)(lat + (size_t)r0 * L + t * 4);
    *(float4*)&ls[t * 4] = v;
  }
  __syncthreads();

  float acc[8][2];
#pragma unroll
  for (int r = 0; r < 8; ++r) { acc[r][0] = 0.f; acc[r][1] = 0.f; }

#pragma unroll 4
  for (int l = 0; l < L; ++l) {
    float w0 = W[l * D + t];
    float w1 = W[l * D + t + 256];
#pragma unroll
    for (int r = 0; r < 8; ++r) {
      float x = ls[r * L + l];
      acc[r][0] = fmaf(x, w0, acc[r][0]);
      acc[r][1] = fmaf(x, w1, acc[r][1]);
    }
  }
  float b0 = bias[t], b1 = bias[t + 256];
#pragma unroll
  for (int r = 0; r < 8; ++r) {
    out[(size_t)(r0 + r) * D + t] = acc[r][0] + b0;
    out[(size_t)(r0 + r) * D + t + 256] = acc[r][1] + b1;
  }
}

// ============ FAST PATH ============
// Quantize + pack + transpose one 64-row tile of one source matrix into
// dst[pd][N] layout. grid (N/64, 3): y=0 gt, y=1 rec_test, y=2 rec_train.
#define PKR 64
__global__ __launch_bounds__(256) void pack_kernel(
    const float* __restrict__ gt, const float* __restrict__ rec_test,
    const float* __restrict__ rec_train, unsigned* __restrict__ Gq,
    unsigned* __restrict__ Aq, unsigned* __restrict__ Tq) {
  const int which = blockIdx.y;
  const float* __restrict__ src =
      which == 0 ? gt : (which == 1 ? rec_test : rec_train);
  unsigned* __restrict__ dst = which == 0 ? Gq : (which == 1 ? Aq : Tq);
  const int i0 = blockIdx.x * PKR;
  const int tid = threadIdx.x;

  __shared__ unsigned ls[PKR][NP8 + 1];  // +1 pad -> conflict-free col reads

  // 64 rows x 128 float4 = 8192 float4; 32 per thread, coalesced 1KB/wave
#pragma unroll 4
  for (int s = 0; s < 32; ++s) {
    int flat = tid + s * 256;
    int row = flat >> 7;
    int c4 = flat & 127;
    float4 v = *(const float4*)(src + (size_t)(i0 + row) * D + c4 * 4);
    ls[row][c4] = pack4(v);
  }
  __syncthreads();

  // write out transposed: wave writes 64 consecutive i per pd (256B stores)
#pragma unroll 4
  for (int s = 0; s < 32; ++s) {
    int flat = tid + s * 256;
    int pd = flat >> 6;
    int i = flat & 63;
    dst[(size_t)pd * N + i0 + i] = ls[i][pd];
  }
}

// L1 cdist on packed u8 quads. Block = 4 waves; wave owns 16 rows (A values
// wave-uniform -> scalar loads), lane owns 2 cols. 32 v_sad_u8 per pd per
// thread = 8 element-pairs per VALU instr. No LDS, no barriers.
__global__ __launch_bounds__(256) __attribute__((amdgpu_waves_per_eu(8)))
void dist_sad_kernel(const unsigned* __restrict__ Aq,
                     const unsigned* __restrict__ Gq,
                     const unsigned* __restrict__ Tq,
                     float* __restrict__ dist) {
  const int i0 = blockIdx.x * BI;
  const int j0 = blockIdx.y * BJ;
  const int mat = blockIdx.z;
  const unsigned* __restrict__ Bq = mat ? Tq : Gq;
  float* __restrict__ out = dist + (size_t)mat * N * N;

  const int wave = threadIdx.x >> 6;
  const int lane = threadIdx.x & 63;
  const int iw = __builtin_amdgcn_readfirstlane(i0 + wave * 16);

  const unsigned* __restrict__ ap = Aq + iw;            // uniform per wave
  const unsigned* __restrict__ bp = Bq + j0 + 2 * lane; // coalesced per wave

  unsigned acc[16][2];
#pragma unroll
  for (int r = 0; r < 16; ++r) { acc[r][0] = 0u; acc[r][1] = 0u; }

#pragma unroll 4
  for (int pd = 0; pd < NP8; ++pd) {
    uint4 a0 = *(const uint4*)(ap);
    uint4 a1 = *(const uint4*)(ap + 4);
    uint4 a2 = *(const uint4*)(ap + 8);
    uint4 a3 = *(const uint4*)(ap + 12);
    uint2 b = *(const uint2*)(bp);
    ap += N;
    bp += N;
#define SADQ(q, base)                                     \
    acc[base + 0][0] = sad8(q.x, b.x, acc[base + 0][0]);  \
    acc[base + 0][1] = sad8(q.x, b.y, acc[base + 0][1]);  \
    acc[base + 1][0] = sad8(q.y, b.x, acc[base + 1][0]);  \
    acc[base + 1][1] = sad8(q.y, b.y, acc[base + 1][1]);  \
    acc[base + 2][0] = sad8(q.z, b.x, acc[base + 2][0]);  \
    acc[base + 2][1] = sad8(q.z, b.y, acc[base + 2][1]);  \
    acc[base + 3][0] = sad8(q.w, b.x, acc[base + 3][0]);  \
    acc[base + 3][1] = sad8(q.w, b.y, acc[base + 3][1]);
    SADQ(a0, 0) SADQ(a1, 4) SADQ(a2, 8) SADQ(a3, 12)
#undef SADQ
  }

  const float sc = 1.0f / 16.0f;
#pragma unroll
  for (int r = 0; r < 16; ++r) {
    float2 dv = make_float2((float)acc[r][0] * sc, (float)acc[r][1] * sc);
    *(float2*)(out + (size_t)(iw + r) * N + j0 + 2 * lane) = dv;
  }
}

// One WAVE per row (4 rows per 256-block, grid 2N/4): insert-filtered scan of
// 64 elems/lane, then 6 shfl_xor bitonic merge levels. No LDS, no barriers.
__global__ __launch_bounds__(256) void row_topk_kernel(
    const float* __restrict__ dist, float* __restrict__ scores) {
  const int wave = threadIdx.x >> 6;
  const int lane = threadIdx.x & 63;
  const int row = blockIdx.x * 4 + wave;
  const float* __restrict__ p = dist + (size_t)row * N;

  float tk[16];
#pragma unroll
  for (int k = 0; k < 16; ++k) tk[k] = 3.0e38f;

#pragma unroll 1
  for (int q = 0; q < 16; ++q) {  // each q: wave reads 1 KB contiguous
    float4 v = *(const float4*)(p + q * 256 + lane * 4);
    if (v.x < tk[15]) topk_insert(tk, v.x);
    if (v.y < tk[15]) topk_insert(tk, v.y);
    if (v.z < tk[15]) topk_insert(tk, v.z);
    if (v.w < tk[15]) topk_insert(tk, v.w);
  }

  // recursive-doubling merge: after level m, lanes in each 2m-group identical
#pragma unroll
  for (int m = 1; m < 64; m <<= 1) {
    float oth[16];
#pragma unroll
    for (int k = 0; k < 16; ++k) oth[k] = __shfl_xor(tk[k], m, 64);
    // half-cleaner: lowest 16 of union, result is bitonic
    float lo[16];
#pragma unroll
    for (int k = 0; k < 16; ++k) lo[k] = fminf(tk[k], oth[15 - k]);
    // bitonic sort of a bitonic 16-seq: stages 8,4,2,1 (constant-indexed)
#pragma unroll
    for (int dlt = 8; dlt >= 1; dlt >>= 1) {
#pragma unroll
      for (int i = 0; i < 16; ++i) {
        if ((i & dlt) == 0 && (i + dlt) < 16) {
          float a = lo[i], b = lo[i + dlt];
          lo[i] = fminf(a, b);
          lo[i + dlt] = fmaxf(a, b);
        }
      }
    }
#pragma unroll
    for (int k = 0; k < 16; ++k) tk[k] = lo[k];
  }

  if (lane == 0) {
    float s = 0.f;
#pragma unroll
    for (int k = 0; k < 16; ++k) s += 1.0f / tk[k];
    scores[row] = s * (1.0f / 16.0f);
  }
}

// ============ FALLBACK PATH (R3, proven) ============
__global__ __launch_bounds__(256) void dist_topk_kernel(
    const float* __restrict__ Arec, const float* __restrict__ Bgt,
    const float* __restrict__ Btr, float* __restrict__ cand) {
  const int itile = blockIdx.x;
  const int part = blockIdx.y;
  const int mat = blockIdx.z;
  const float* __restrict__ B = mat ? Btr : Bgt;
  const int i0 = itile * TI;
  const int jbase = part * PARTJ;

  __shared__ float smem[SMEM_FLOATS];
  float* As = smem;
  float* Bs = smem + KD * AS_STRIDE;
  float* distS = smem;

  const int tid = threadIdx.x;
  const int tx = tid & 15;
  const int ty = tid >> 4;
  const int srow = tid >> 1;
  const int shalf = tid & 1;
  const int scol = shalf * 32;

  float tk[16];
#pragma unroll
  for (int k = 0; k < 16; ++k) tk[k] = 3.0e38f;

  for (int jc = 0; jc < PARTJ; jc += TJ) {
    float acc[8][4];
#pragma unroll
    for (int r = 0; r < 8; ++r)
#pragma unroll
      for (int c = 0; c < 4; ++c) acc[r][c] = 0.f;

    for (int d0 = 0; d0 < D; d0 += KD) {
      __syncthreads();
#pragma unroll
      for (int s = 0; s < 4; ++s) {
        int f4 = tid + s * 256;
        int r = f4 >> 3;
        int c4 = f4 & 7;
        float4 v = *(const float4*)(Arec + (size_t)(i0 + r) * D + d0 + c4 * 4);
        As[(4 * c4 + 0) * AS_STRIDE + r] = v.x;
        As[(4 * c4 + 1) * AS_STRIDE + r] = v.y;
        As[(4 * c4 + 2) * AS_STRIDE + r] = v.z;
        As[(4 * c4 + 3) * AS_STRIDE + r] = v.w;
      }
#pragma unroll
      for (int s = 0; s < 2; ++s) {
        int f4 = tid + s * 256;
        int r = f4 >> 3;
        int c4 = f4 & 7;
        float4 v = *(const float4*)(B + (size_t)(jbase + jc + r) * D + d0 + c4 * 4);
        Bs[(4 * c4 + 0) * BS_STRIDE + r] = v.x;
        Bs[(4 * c4 + 1) * BS_STRIDE + r] = v.y;
        Bs[(4 * c4 + 2) * BS_STRIDE + r] = v.z;
        Bs[(4 * c4 + 3) * BS_STRIDE + r] = v.w;
      }
      __syncthreads();

#pragma unroll
      for (int d = 0; d < KD; ++d) {
        float4 a0 = *(const float4*)&As[d * AS_STRIDE + 8 * ty];
        float4 a1 = *(const float4*)&As[d * AS_STRIDE + 8 * ty + 4];
        float4 bv4 = *(const float4*)&Bs[d * BS_STRIDE + 4 * tx];
        float av[8] = {a0.x, a0.y, a0.z, a0.w, a1.x, a1.y, a1.z, a1.w};
        float bv[4] = {bv4.x, bv4.y, bv4.z, bv4.w};
#pragma unroll
        for (int r = 0; r < 8; ++r)
#pragma unroll
          for (int c = 0; c < 4; ++c) acc[r][c] += __builtin_fabsf(av[r] - bv[c]);
      }
    }

    __syncthreads();
#pragma unroll
    for (int r = 0; r < 8; ++r)
      *(float4*)&distS[(8 * ty + r) * DS_STRIDE + 4 * tx] =
          make_float4(acc[r][0], acc[r][1], acc[r][2], acc[r][3]);
    __syncthreads();

#pragma unroll 1
    for (int j4 = 0; j4 < 8; ++j4) {
      float4 v = *(const float4*)&distS[srow * DS_STRIDE + scol + j4 * 4];
      if (v.x < tk[15]) topk_insert(tk, v.x);
      if (v.y < tk[15]) topk_insert(tk, v.y);
      if (v.z < tk[15]) topk_insert(tk, v.z);
      if (v.w < tk[15]) topk_insert(tk, v.w);
    }
  }

  __syncthreads();
  float* mergeS = smem;
#pragma unroll
  for (int k4 = 0; k4 < 4; ++k4)
    *(float4*)&mergeS[srow * 32 + shalf * 16 + k4 * 4] =
        make_float4(tk[k4 * 4], tk[k4 * 4 + 1], tk[k4 * 4 + 2], tk[k4 * 4 + 3]);
  __syncthreads();

  if (tid < TI) {
    const float* LA = &mergeS[tid * 32];
    const float* LB = LA + 16;
    const int row = i0 + tid;
    float* dst = cand + ((size_t)((mat * PARTS + part) * N) + row) * 16;
    int ia = 0, ib = 0;
#pragma unroll 1
    for (int k = 0; k < 16; ++k) {
      float a = LA[ia < 16 ? ia : 15];
      float b = LB[ib < 16 ? ib : 15];
      bool takeA = (ib >= 16) || (ia < 16 && a <= b);
      dst[k] = takeA ? a : b;
      ia += takeA ? 1 : 0;
      ib += takeA ? 0 : 1;
    }
  }
}

__global__ __launch_bounds__(256) void merge_kernel(
    const float* __restrict__ cand, float* __restrict__ scores) {
  const int gid = blockIdx.x * 256 + threadIdx.x;
  if (gid >= 2 * N) return;
  const int m = gid >> 12;
  const int row = gid & (N - 1);

  float tk[16];
#pragma unroll
  for (int k = 0; k < 16; ++k) tk[k] = 3.0e38f;

  for (int p = 0; p < PARTS; ++p) {
    const float* lp = cand + ((size_t)((m * PARTS + p) * N) + row) * 16;
#pragma unroll 1
    for (int k = 0; k < 16; ++k) {
      float v = lp[k];
      if (v >= tk[15]) break;
      topk_insert(tk, v);
    }
  }
  float s = 0.f;
#pragma unroll
  for (int k = 0; k < 16; ++k) s += 1.0f / tk[k];
  scores[(size_t)m * N + row] = s * (1.0f / 16.0f);
}

// losses = relu(neg - pos); huber(delta=1) vs 0; mean. Single block.
__global__ __launch_bounds__(256) void loss_kernel(
    const float* __restrict__ scores, float* __restrict__ out) {
  const int tid = threadIdx.x;
  float s = 0.f;
  for (int i = tid; i < N; i += 256) {
    float l = scores[N + i] - scores[i];
    l = fmaxf(l, 0.f);
    s += (l <= 1.f) ? 0.5f * l * l : (l - 0.5f);
  }
#pragma unroll
  for (int off = 32; off > 0; off >>= 1) s += __shfl_down(s, off, 64);
  __shared__ float ws[4];
  if ((tid & 63) == 0) ws[tid >> 6] = s;
  __syncthreads();
  if (tid == 0) {
    float t = ws[0] + ws[1] + ws[2] + ws[3];
    out[0] = t * (1.0f / (float)N);
  }
}

extern "C" void kernel_launch(void* const* d_in, const int* in_sizes, int n_in,
                              void* d_out, int out_size, void* d_ws, size_t ws_size,
                              hipStream_t stream) {
  const float* gt_vals = (const float*)d_in[0];
  const float* train_latent = (const float*)d_in[1];
  const float* test_latent = (const float*)d_in[2];
  const float* W = (const float*)d_in[3];
  const float* b = (const float*)d_in[4];
  float* out = (float*)d_out;

  char* ws = (char*)d_ws;
  const size_t MB = 1048576;
  const size_t REC = 8 * MB;
  const size_t DIST = 128 * MB;
  const size_t NEED_FAST = 2 * REC + DIST + 32768;

  if (ws_size >= NEED_FAST) {
    // layout: [0,2M) Aq(test), [2,4M) Tq(train), [4,6M) Gq(gt),
    // [6M,+32K) scores, [16M,144M) dist; rec f32 live transiently at
    // [16M,24M)/[24M,32M) inside the dist region (dead before dist write).
    unsigned* Aq = (unsigned*)(ws);
    unsigned* Tq = (unsigned*)(ws + 2 * MB);
    unsigned* Gq = (unsigned*)(ws + 4 * MB);
    float* scores = (float*)(ws + 6 * MB);
    float* dist = (float*)(ws + 16 * MB);
    float* rec_test = (float*)(ws + 16 * MB);
    float* rec_train = (float*)(ws + 24 * MB);

    linear_kernel<<<dim3(N / 8, 2), 256, 0, stream>>>(
        test_latent, train_latent, W, b, rec_test, rec_train);
    pack_kernel<<<dim3(N / PKR, 3), 256, 0, stream>>>(
        gt_vals, rec_test, rec_train, Gq, Aq, Tq);
    dist_sad_kernel<<<dim3(N / BI, N / BJ, 2), 256, 0, stream>>>(
        Aq, Gq, Tq, dist);
    row_topk_kernel<<<(2 * N) / 4, 256, 0, stream>>>(dist, scores);
    loss_kernel<<<1, 256, 0, stream>>>(scores, out);
  } else {
    float* rec_test = (float*)(ws);
    float* rec_train = (float*)(ws + REC);
    float* cand = (float*)(ws + 2 * REC);                 // 8 MB
    float* scores = (float*)(ws + 2 * REC + 8388608);     // 32 KB
    linear_kernel<<<dim3(N / 8, 2), 256, 0, stream>>>(
        test_latent, train_latent, W, b, rec_test, rec_train);
    dist_topk_kernel<<<dim3(N / TI, PARTS, 2), 256, 0, stream>>>(
        rec_test, gt_vals, rec_train, cand);
    merge_kernel<<<(2 * N) / 256, 256, 0, stream>>>(cand, scores);
    loss_kernel<<<1, 256, 0, stream>>>(scores, out);
  }
}